// Round 16
// baseline (125.136 us; speedup 1.0000x reference)
//
#include <hip/hip_runtime.h>
#include <math.h>

#define B_ 16
#define P_ 19248
#define C_ 81
#define O_ 32
#define POS_TH 0.5f
#define NEG_TH 0.4f
#define RPB 128              // rows per k_main block (2 x 64-row pipelined halves)
#define TPB 512              // 8 waves; 8 threads/row on each 64-row half
#define PQ  4812             // P_/4: priors per best_prior quarter-block
#define BP_BLK (B_ * O_ * 4) // 2048 best_prior quarter blocks
#define BT_BPB 76            // ceil(P_/256) best_truth blocks per batch
#define OT 1024              // k_ohem threads (16 waves)
#define NJ 19                // ceil(P_/OT) per-thread elements in k_ohem

#define AS1 const __attribute__((address_space(1))) void*
#define AS3 __attribute__((address_space(3))) void*

__device__ __forceinline__ float sl1(float x) {
    float d = fabsf(x);
    return (d < 1.0f) ? 0.5f * d * d : d - 0.5f;
}

__device__ __forceinline__ float iou_gt_prior(float4 t, float4 pr) {
    float px1 = pr.x - pr.z * 0.5f;
    float py1 = pr.y - pr.w * 0.5f;
    float px2 = pr.x + pr.z * 0.5f;
    float py2 = pr.y + pr.w * 0.5f;
    float ltx = fmaxf(t.x, px1), lty = fmaxf(t.y, py1);
    float rbx = fminf(t.z, px2), rby = fminf(t.w, py2);
    float iw = fmaxf(rbx - ltx, 0.0f), ih = fmaxf(rby - lty, 0.0f);
    float inter = iw * ih;
    float area_t = (t.z - t.x) * (t.w - t.y);
    float area_p = (px2 - px1) * (py2 - py1);
    return inter / (area_t + area_p - inter);
}

// ---- parallel threshold picks for OT=1024 threads (16 waves) ----
template <int PER>
__device__ __forceinline__ void pick_top(const int* __restrict__ h, int kk, int tid,
                                         int* s_bin, int* s_kk, int* wsum) {
    const int lane = tid & 63, wid = tid >> 6;
    const int base = tid * PER;
    int v[PER]; int s = 0;
    #pragma unroll
    for (int j = 0; j < PER; ++j) { v[j] = h[base + j]; s += v[j]; }
    int x = s;                                  // inclusive suffix scan in wave
    #pragma unroll
    for (int d = 1; d < 64; d <<= 1) {
        int y = __shfl_down(x, d);
        if (lane + d < 64) x += y;
    }
    if (lane == 0) wsum[wid] = x;
    __syncthreads();
    int above = 0;
    #pragma unroll
    for (int w = 0; w < 16; ++w) if (w > wid) above += wsum[w];
    int T = (x - s) + above;
    if (T < kk && kk <= T + s) {                // exactly one thread true
        int kl = kk - T, cum = 0;
        #pragma unroll
        for (int j = PER - 1; j >= 0; --j) {
            if (cum + v[j] >= kl) { *s_bin = base + j; *s_kk = kl - cum; break; }
            cum += v[j];
        }
    }
    __syncthreads();
}

template <int PER>
__device__ __forceinline__ void pick_bot(const int* __restrict__ h, int kk, int tid,
                                         int* s_bin, int* s_kk, int* wsum) {
    const int lane = tid & 63, wid = tid >> 6;
    const int base = tid * PER;
    int v[PER]; int s = 0;
    #pragma unroll
    for (int j = 0; j < PER; ++j) { v[j] = h[base + j]; s += v[j]; }
    int x = s;                                  // inclusive prefix scan in wave
    #pragma unroll
    for (int d = 1; d < 64; d <<= 1) {
        int y = __shfl_up(x, d);
        if (lane >= d) x += y;
    }
    if (lane == 63) wsum[wid] = x;
    __syncthreads();
    int below = 0;
    #pragma unroll
    for (int w = 0; w < 16; ++w) if (w < wid) below += wsum[w];
    int T = (x - s) + below;
    if (T < kk && kk <= T + s) {
        int kl = kk - T, cum = 0;
        #pragma unroll
        for (int j = 0; j < PER; ++j) {
            if (cum + v[j] >= kl) { *s_bin = base + j; *s_kk = kl - cum; break; }
            cum += v[j];
        }
    }
    __syncthreads();
}

// Merged matcher (R12-verified; pure matcher, no cross-block write hazards).
__global__ void k_match(const float* __restrict__ priors,
                        const float* __restrict__ gt_boxes,
                        const int* __restrict__ gt_labels,
                        unsigned long long* __restrict__ best_key,
                        float* __restrict__ bt_ov,
                        int* __restrict__ bt_ix,
                        int* __restrict__ bt_lab) {
    const int bid = blockIdx.x;
    if (bid < BP_BLK) {
        int pair = bid >> 2, qtr = bid & 3;
        int b = pair >> 5, o = pair & 31;
        float4 t = ((const float4*)gt_boxes)[b * O_ + o];
        float bestv = -1.0f; int besti = 0;
        int pstart = qtr * PQ;
        for (int p = pstart + threadIdx.x; p < pstart + PQ; p += 256) {
            float4 pr = ((const float4*)priors)[p];
            float v = iou_gt_prior(t, pr);
            if (v > bestv) { bestv = v; besti = p; }
        }
        __shared__ float sv[256];
        __shared__ int   si[256];
        sv[threadIdx.x] = bestv; si[threadIdx.x] = besti;
        __syncthreads();
        for (int s = 128; s > 0; s >>= 1) {
            if (threadIdx.x < s) {
                float ov = sv[threadIdx.x + s]; int oi = si[threadIdx.x + s];
                if (ov > sv[threadIdx.x] ||
                    (ov == sv[threadIdx.x] && oi < si[threadIdx.x])) {
                    sv[threadIdx.x] = ov; si[threadIdx.x] = oi;
                }
            }
            __syncthreads();
        }
        if (threadIdx.x == 0) {
            unsigned long long key =
                ((unsigned long long)__float_as_uint(sv[0]) << 32) |
                (unsigned long long)(0xFFFFFFFFu - (unsigned int)si[0]);
            atomicMax(&best_key[pair], key);
        }
    } else {
        int idx = bid - BP_BLK;
        int b = idx / BT_BPB;
        int p = (idx % BT_BPB) * 256 + threadIdx.x;
        __shared__ float4 gt[O_];
        __shared__ int    gl[O_];
        if (threadIdx.x < O_) {
            gt[threadIdx.x] = ((const float4*)gt_boxes)[b * O_ + threadIdx.x];
            gl[threadIdx.x] = gt_labels[b * O_ + threadIdx.x];
        }
        __syncthreads();
        if (p >= P_) return;
        float4 pr = ((const float4*)priors)[p];
        float bestv = -1.0f; int besti = 0;
        for (int o = 0; o < O_; ++o) {
            float v = iou_gt_prior(gt[o], pr);
            if (v > bestv) { bestv = v; besti = o; }
        }
        size_t bp = (size_t)b * P_ + p;
        bt_ov[bp] = bestv;
        bt_ix[bp] = besti;
        bt_lab[bp] = gl[besti];
    }
}

// 64-row half-tile compute: 8 threads/row logsumexp + classification + losses.
__device__ __forceinline__ void compute_half(
    const float* __restrict__ buf, int rowbase, int b0,
    const int s_fp[2][O_], const int s_fl[2][O_],
    const float* __restrict__ loc_data, const float* __restrict__ priors,
    const float* __restrict__ gt_boxes,
    const float* __restrict__ bt_ov, const int* __restrict__ bt_ix,
    const int* __restrict__ bt_lab,
    float* __restrict__ lossc, float* __restrict__ ce_neg,
    float* s_lB, float* s_ceP, int* s_np0, int* s_np1, int tid)
{
    const int r = tid >> 3;               // row within half
    const int q = tid & 7;                // sub-row worker (8 per row)
    const int bp = rowbase + r;
    const int b = bp / P_;
    const int p = bp - b * P_;
    const float* row = buf + r * C_;
    const int j0 = 10 * q;

    float ma = row[j0], mb = row[j0 + 1];
    #pragma unroll
    for (int i = 2; i < 10; i += 2) {
        ma = fmaxf(ma, row[j0 + i]);
        mb = fmaxf(mb, row[j0 + i + 1]);
    }
    float m = fmaxf(ma, mb);
    if (q == 7) m = fmaxf(m, row[80]);
    m = fmaxf(m, __shfl_xor(m, 1));
    m = fmaxf(m, __shfl_xor(m, 2));
    m = fmaxf(m, __shfl_xor(m, 4));

    float sa = 0.f, sb = 0.f;
    #pragma unroll
    for (int i = 0; i < 10; i += 2) {
        sa += __expf(row[j0 + i] - m);
        sb += __expf(row[j0 + i + 1] - m);
    }
    float s = sa + sb;
    if (q == 7) s += __expf(row[80] - m);
    s += __shfl_xor(s, 1);
    s += __shfl_xor(s, 2);
    s += __shfl_xor(s, 4);
    float logZ = m + __logf(s);

    if (q == 0) {
        // force-match check: scan oo=31..0, first hit = last-wins
        const int whichb = b - b0;
        int foo = -1;
        #pragma unroll
        for (int oo = O_ - 1; oo >= 0; --oo) {
            if (foo < 0 && s_fp[whichb][oo] == p) foo = oo;
        }
        int conf_t, ti = 0;
        bool pos;
        if (foo >= 0) {                   // forced: ov=2.0 -> positive
            conf_t = s_fl[whichb][foo] + 1;
            pos = true;
            ti = foo;
        } else {
            float ov = bt_ov[bp];
            conf_t = bt_lab[bp] + 1;
            if (ov < POS_TH) conf_t = -1;
            if (ov < NEG_TH) conf_t = 0;
            pos = conf_t > 0;
            if (pos) ti = bt_ix[bp];
        }

        float lc = (pos || conf_t < 0) ? 0.0f : (logZ - row[0]);
        int cls = pos ? conf_t : 0;
        float ce = logZ - row[cls];

        lossc[bp] = lc;
        ce_neg[bp] = (conf_t == 0) ? ce : 0.0f;

        if (pos) {
            float4 t = ((const float4*)gt_boxes)[b * O_ + ti];
            float4 pr = ((const float4*)priors)[p];
            float mcx = (t.x + t.z) * 0.5f;
            float mcy = (t.y + t.w) * 0.5f;
            float gx = (mcx - pr.x) / (0.1f * pr.z);
            float gy = (mcy - pr.y) / (0.1f * pr.w);
            float gw = logf((t.z - t.x) / pr.z) / 0.2f;
            float gh = logf((t.w - t.y) / pr.w) / 0.2f;
            float4 ld = ((const float4*)loc_data)[bp];
            float sc2 = sl1(ld.x - gx) + sl1(ld.y - gy) + sl1(ld.z - gw) + sl1(ld.w - gh);
            atomicAdd(s_lB, sc2);
            atomicAdd(s_ceP, ce);
            if (b == b0) atomicAdd(s_np0, 1); else atomicAdd(s_np1, 1);
        }
    }
}

// Main pass, 2-phase intra-block pipeline: stage half0 -> drain -> ISSUE
// half1 (global_load_lds has no dest registers, cannot be sunk by regalloc
// -- the R7 failure mode doesn't apply) -> compute half0 while half1's
// loads fly -> barrier drains half1 -> compute half1. Separate __shared__
// arrays so alias analysis can't force a vmcnt wait before half0's ds_reads.
__global__ __launch_bounds__(TPB, 6) void
k_main(const float* __restrict__ loc_data,
       const float* __restrict__ conf_data,
       const float* __restrict__ priors,
       const float* __restrict__ gt_boxes,
       const int* __restrict__ gt_labels,
       const unsigned long long* __restrict__ best_key,
       const float* __restrict__ bt_ov,
       const int* __restrict__ bt_ix,
       const int* __restrict__ bt_lab,
       float* __restrict__ lossc,
       float* __restrict__ ce_neg,
       int* __restrict__ num_pos,
       float* __restrict__ accum) {
    __shared__ float srowA[64 * C_];      // 20736 B
    __shared__ float srowB[64 * C_];      // 20736 B
    __shared__ int s_fp[2][O_];           // forced prior per (batch-half, o)
    __shared__ int s_fl[2][O_];           // its label
    __shared__ float s_lB, s_ceP;
    __shared__ int s_np0, s_np1;
    const int row0 = blockIdx.x * RPB;
    const int b0 = row0 / P_;
    const int tid = threadIdx.x;
    const int w = tid >> 6;
    if (tid == 0) { s_lB = 0.0f; s_ceP = 0.0f; s_np0 = 0; s_np1 = 0; }

    {   // stage half 0 -> A: 1296 float4 = 2 full rounds + 272 tail
        const float4* src = (const float4*)(conf_data + (size_t)row0 * C_);
        float4* dst4 = (float4*)srowA;
        __builtin_amdgcn_global_load_lds((AS1)(src + tid),
                                         (AS3)(dst4 + (w << 6)), 16, 0, 0);
        __builtin_amdgcn_global_load_lds((AS1)(src + 512 + tid),
                                         (AS3)(dst4 + 512 + (w << 6)), 16, 0, 0);
        if (tid < 272)
            __builtin_amdgcn_global_load_lds((AS1)(src + 1024 + tid),
                                             (AS3)(dst4 + 1024 + (w << 6)), 16, 0, 0);
    }
    // stage force-match table for this block's <=2 batches
    if (tid < 2 * O_) {
        int half = tid >> 5, o = tid & 31;
        int bb = b0 + half;
        int fp = -1, fl = 0;
        if (bb < B_) {
            unsigned long long key = best_key[bb * O_ + o];
            fp = (int)(0xFFFFFFFFu - (unsigned int)(key & 0xFFFFFFFFu));
            fl = gt_labels[bb * O_ + o];
        }
        s_fp[half][o] = fp;
        s_fl[half][o] = fl;
    }
    __syncthreads();                      // drain half0 + table

    {   // ISSUE stage half 1 -> B; lands during compute of half 0
        const float4* src = (const float4*)(conf_data + (size_t)(row0 + 64) * C_);
        float4* dst4 = (float4*)srowB;
        __builtin_amdgcn_global_load_lds((AS1)(src + tid),
                                         (AS3)(dst4 + (w << 6)), 16, 0, 0);
        __builtin_amdgcn_global_load_lds((AS1)(src + 512 + tid),
                                         (AS3)(dst4 + 512 + (w << 6)), 16, 0, 0);
        if (tid < 272)
            __builtin_amdgcn_global_load_lds((AS1)(src + 1024 + tid),
                                             (AS3)(dst4 + 1024 + (w << 6)), 16, 0, 0);
    }

    compute_half(srowA, row0, b0, s_fp, s_fl, loc_data, priors, gt_boxes,
                 bt_ov, bt_ix, bt_lab, lossc, ce_neg,
                 &s_lB, &s_ceP, &s_np0, &s_np1, tid);
    __syncthreads();                      // drain half1 (overlapped w/ compute)
    compute_half(srowB, row0 + 64, b0, s_fp, s_fl, loc_data, priors, gt_boxes,
                 bt_ov, bt_ix, bt_lab, lossc, ce_neg,
                 &s_lB, &s_ceP, &s_np0, &s_np1, tid);
    __syncthreads();
    if (tid == 0) {
        if (s_lB != 0.0f) atomicAdd(&accum[0], s_lB);
        if (s_ceP != 0.0f) atomicAdd(&accum[1], s_ceP);
        if (s_np0) atomicAdd(&num_pos[b0], s_np0);
        if (s_np1) atomicAdd(&num_pos[b0 + 1], s_np1);   // block spans <=2 batches
    }
}

// One block per batch, 1024 threads: register-cached radix select (exact
// stable-argsort semantics). Sentinels (i >= P_) use fb=0, cv=0 (R14-verified).
__global__ __launch_bounds__(OT) void
k_ohem(const float* __restrict__ lossc, const float* __restrict__ ce_neg,
       const int* __restrict__ num_pos, const float* __restrict__ accum,
       float* __restrict__ ce_sum, int* __restrict__ done,
       float* __restrict__ out) {
    const int b = blockIdx.x;
    const int tid = threadIdx.x;
    const float* lc = lossc + (size_t)b * P_;
    const float* cn = ce_neg + (size_t)b * P_;
    __shared__ int h[2048];
    __shared__ int wsum[16];
    __shared__ int s_bin, s_kk;
    __shared__ float red[OT];

    int k = 3 * num_pos[b];
    if (k > P_ - 1) k = P_ - 1;

    float result = 0.0f;
    if (k > 0) {
        unsigned int fb[NJ]; float cv[NJ];
        #pragma unroll
        for (int j = 0; j < NJ; ++j) {
            int i = tid + j * OT;
            bool valid = (i < P_);
            fb[j] = valid ? __float_as_uint(lc[i]) : 0u;   // bottom-ranked sentinel
            cv[j] = valid ? cn[i] : 0.0f;
        }
        // round 0: 1024-bin hist of fb>>21 (monotone, lossc >= 0)
        h[tid] = 0; h[tid + 1024] = 0;
        __syncthreads();
        #pragma unroll
        for (int j = 0; j < NJ; ++j) atomicAdd(&h[fb[j] >> 21], 1);
        __syncthreads();
        pick_top<2>(h, k, tid, &s_bin, &s_kk, wsum);
        const unsigned int T = (unsigned int)s_bin;
        int kk = s_kk;

        // pass A: sum ce for bins > T; hist bits 20..10 of bin==T
        h[tid] = 0; h[tid + 1024] = 0;
        __syncthreads();
        float sum = 0.0f;
        #pragma unroll
        for (int j = 0; j < NJ; ++j) {
            unsigned int bin = fb[j] >> 21;
            if (bin > T) sum += cv[j];
            else if (bin == T) atomicAdd(&h[(fb[j] >> 10) & 2047], 1);
        }
        __syncthreads();
        pick_top<2>(h, kk, tid, &s_bin, &s_kk, wsum);
        const unsigned int pre21 = (T << 11) | (unsigned int)s_bin;
        kk = s_kk;

        // pass B: hist bits 9..0 of elements matching top 22 bits
        h[tid] = 0; h[tid + 1024] = 0;
        __syncthreads();
        #pragma unroll
        for (int j = 0; j < NJ; ++j)
            if ((fb[j] >> 10) == pre21) atomicAdd(&h[fb[j] & 1023], 1);
        __syncthreads();
        pick_top<2>(h, kk, tid, &s_bin, &s_kk, wsum);
        const unsigned int V = (pre21 << 10) | (unsigned int)s_bin;
        const int ee = h[s_bin];
        kk = s_kk;

        if (kk == ee) {
            #pragma unroll
            for (int j = 0; j < NJ; ++j)
                if ((fb[j] >> 21) == T && fb[j] >= V) sum += cv[j];
        } else {
            // kk smallest-index elements with fb == V (stable argsort ties);
            // sentinels at fb==0==V lose by index and carry cv=0.
            h[tid] = 0; h[tid + 1024] = 0;
            __syncthreads();
            #pragma unroll
            for (int j = 0; j < NJ; ++j)
                if (fb[j] == V) atomicAdd(&h[(tid + j * OT) >> 6], 1);
            __syncthreads();
            pick_bot<2>(h, kk, tid, &s_bin, &s_kk, wsum);
            const int d6 = s_bin;
            kk = s_kk;
            h[tid] = 0; h[tid + 1024] = 0;
            __syncthreads();
            #pragma unroll
            for (int j = 0; j < NJ; ++j) {
                int i = tid + j * OT;
                if (fb[j] == V && (i >> 6) == d6) atomicAdd(&h[i & 63], 1);
            }
            __syncthreads();
            pick_bot<2>(h, kk, tid, &s_bin, &s_kk, wsum);
            const int Istar = (d6 << 6) | s_bin;
            #pragma unroll
            for (int j = 0; j < NJ; ++j) {
                int i = tid + j * OT;
                if ((fb[j] >> 21) == T && (fb[j] > V || (fb[j] == V && i <= Istar)))
                    sum += cv[j];
            }
        }

        red[tid] = sum;
        __syncthreads();
        for (int s = OT / 2; s > 0; s >>= 1) {
            if (tid < s) red[tid] += red[tid + s];
            __syncthreads();
        }
        result = red[0];
    }

    if (tid == 0) {
        ce_sum[b] = result;
        __threadfence();
        int old = atomicAdd(done, 1);
        if (old == B_ - 1) {                  // last block folds the output
            __threadfence();
            int tp = 0; float ns = 0.0f;
            for (int bb = 0; bb < B_; ++bb) { tp += num_pos[bb]; ns += ce_sum[bb]; }
            float inv = 1.0f / (float)tp;
            out[0] = accum[0] * 1.5f * inv;   // BBOX_ALPHA
            out[1] = (accum[1] + ns) * inv;   // CONF_ALPHA
        }
    }
}

extern "C" void kernel_launch(void* const* d_in, const int* in_sizes, int n_in,
                              void* d_out, int out_size, void* d_ws, size_t ws_size,
                              hipStream_t stream) {
    const float* loc    = (const float*)d_in[0];
    const float* conf   = (const float*)d_in[1];
    const float* priors = (const float*)d_in[2];
    const float* gtb    = (const float*)d_in[3];
    const int*   gtl    = (const int*)d_in[4];
    float* out = (float*)d_out;

    const size_t BP = (size_t)B_ * P_;
    float* W = (float*)d_ws;
    float* bt_ov   = W;
    float* lossc   = W + BP;
    float* ce_neg  = W + 2 * BP;
    int*   bt_ix   = (int*)(W + 3 * BP);
    int*   bt_lab  = (int*)(W + 4 * BP);
    unsigned long long* best_key = (unsigned long long*)(W + 5 * BP);  // 8B-aligned
    int*   num_pos = (int*)(best_key + B_ * O_);
    float* ce_sum  = (float*)(num_pos + B_);
    float* accum   = ce_sum + B_;
    int*   done    = (int*)(accum + 2);

    // zero best_key + num_pos + ce_sum + accum + done in one memset
    size_t zbytes = B_ * O_ * sizeof(unsigned long long) +
                    B_ * sizeof(int) + B_ * sizeof(float) +
                    2 * sizeof(float) + sizeof(int);
    hipMemsetAsync(best_key, 0, zbytes, stream);
    hipLaunchKernelGGL(k_match, dim3(BP_BLK + B_ * BT_BPB), dim3(256), 0, stream,
                       priors, gtb, gtl, best_key, bt_ov, bt_ix, bt_lab);
    hipLaunchKernelGGL(k_main, dim3((int)(BP / RPB)), dim3(TPB), 0, stream,
                       loc, conf, priors, gtb, gtl, best_key,
                       bt_ov, bt_ix, bt_lab, lossc, ce_neg, num_pos, accum);
    hipLaunchKernelGGL(k_ohem, dim3(B_), dim3(OT), 0, stream,
                       lossc, ce_neg, num_pos, accum, ce_sum, done, out);
}

// Round 17
// 114.828 us; speedup vs baseline: 1.0898x; 1.0898x over previous
//
#include <hip/hip_runtime.h>
#include <math.h>

#define B_ 16
#define P_ 19248
#define C_ 81
#define O_ 32
#define POS_TH 0.5f
#define NEG_TH 0.4f
#define RPB 128              // rows per k_main tile; B_*P_ = 307968 = 2406*128
#define TPB 512              // threads per k_main block (8 waves), 4 threads/row
#define PQ  4812             // P_/4: priors per best_prior quarter-block
#define BP_BLK (B_ * O_ * 4) // 2048 best_prior quarter blocks
#define OT 1024              // k_ohem threads (16 waves)
#define NJ 19                // ceil(P_/OT) per-thread elements in k_ohem

#define AS1 const __attribute__((address_space(1))) void*
#define AS3 __attribute__((address_space(3))) void*

__device__ __forceinline__ float sl1(float x) {
    float d = fabsf(x);
    return (d < 1.0f) ? 0.5f * d * d : d - 0.5f;
}

__device__ __forceinline__ float iou_gt_prior(float4 t, float4 pr) {
    float px1 = pr.x - pr.z * 0.5f;
    float py1 = pr.y - pr.w * 0.5f;
    float px2 = pr.x + pr.z * 0.5f;
    float py2 = pr.y + pr.w * 0.5f;
    float ltx = fmaxf(t.x, px1), lty = fmaxf(t.y, py1);
    float rbx = fminf(t.z, px2), rby = fminf(t.w, py2);
    float iw = fmaxf(rbx - ltx, 0.0f), ih = fmaxf(rby - lty, 0.0f);
    float inter = iw * ih;
    float area_t = (t.z - t.x) * (t.w - t.y);
    float area_p = (px2 - px1) * (py2 - py1);
    return inter / (area_t + area_p - inter);
}

// ---- parallel threshold picks for OT=1024 threads (16 waves) ----
template <int PER>
__device__ __forceinline__ void pick_top(const int* __restrict__ h, int kk, int tid,
                                         int* s_bin, int* s_kk, int* wsum) {
    const int lane = tid & 63, wid = tid >> 6;
    const int base = tid * PER;
    int v[PER]; int s = 0;
    #pragma unroll
    for (int j = 0; j < PER; ++j) { v[j] = h[base + j]; s += v[j]; }
    int x = s;                                  // inclusive suffix scan in wave
    #pragma unroll
    for (int d = 1; d < 64; d <<= 1) {
        int y = __shfl_down(x, d);
        if (lane + d < 64) x += y;
    }
    if (lane == 0) wsum[wid] = x;
    __syncthreads();
    int above = 0;
    #pragma unroll
    for (int w = 0; w < 16; ++w) if (w > wid) above += wsum[w];
    int T = (x - s) + above;
    if (T < kk && kk <= T + s) {                // exactly one thread true
        int kl = kk - T, cum = 0;
        #pragma unroll
        for (int j = PER - 1; j >= 0; --j) {
            if (cum + v[j] >= kl) { *s_bin = base + j; *s_kk = kl - cum; break; }
            cum += v[j];
        }
    }
    __syncthreads();
}

template <int PER>
__device__ __forceinline__ void pick_bot(const int* __restrict__ h, int kk, int tid,
                                         int* s_bin, int* s_kk, int* wsum) {
    const int lane = tid & 63, wid = tid >> 6;
    const int base = tid * PER;
    int v[PER]; int s = 0;
    #pragma unroll
    for (int j = 0; j < PER; ++j) { v[j] = h[base + j]; s += v[j]; }
    int x = s;                                  // inclusive prefix scan in wave
    #pragma unroll
    for (int d = 1; d < 64; d <<= 1) {
        int y = __shfl_up(x, d);
        if (lane >= d) x += y;
    }
    if (lane == 63) wsum[wid] = x;
    __syncthreads();
    int below = 0;
    #pragma unroll
    for (int w = 0; w < 16; ++w) if (w < wid) below += wsum[w];
    int T = (x - s) + below;
    if (T < kk && kk <= T + s) {
        int kl = kk - T, cum = 0;
        #pragma unroll
        for (int j = 0; j < PER; ++j) {
            if (cum + v[j] >= kl) { *s_bin = base + j; *s_kk = kl - cum; break; }
            cum += v[j];
        }
    }
    __syncthreads();
}

// best_prior only (best_truth is fused into k_main): one quarter-block per
// (b,o,qtr); global merge via atomicMax on key = fbits(iou)<<32 | ~p
// (max value, smallest-p tie-break == numpy argmax).
__global__ void k_match(const float* __restrict__ priors,
                        const float* __restrict__ gt_boxes,
                        unsigned long long* __restrict__ best_key) {
    const int bid = blockIdx.x;
    int pair = bid >> 2, qtr = bid & 3;
    int b = pair >> 5, o = pair & 31;
    float4 t = ((const float4*)gt_boxes)[b * O_ + o];
    float bestv = -1.0f; int besti = 0;
    int pstart = qtr * PQ;
    for (int p = pstart + threadIdx.x; p < pstart + PQ; p += 256) {
        float4 pr = ((const float4*)priors)[p];
        float v = iou_gt_prior(t, pr);
        if (v > bestv) { bestv = v; besti = p; }
    }
    __shared__ float sv[256];
    __shared__ int   si[256];
    sv[threadIdx.x] = bestv; si[threadIdx.x] = besti;
    __syncthreads();
    for (int s = 128; s > 0; s >>= 1) {
        if (threadIdx.x < s) {
            float ov = sv[threadIdx.x + s]; int oi = si[threadIdx.x + s];
            if (ov > sv[threadIdx.x] ||
                (ov == sv[threadIdx.x] && oi < si[threadIdx.x])) {
                sv[threadIdx.x] = ov; si[threadIdx.x] = oi;
            }
        }
        __syncthreads();
    }
    if (threadIdx.x == 0) {
        unsigned long long key =
            ((unsigned long long)__float_as_uint(sv[0]) << 32) |
            (unsigned long long)(0xFFFFFFFFu - (unsigned int)si[0]);
        atomicMax(&best_key[pair], key);
    }
}

// Main pass (R14 structure, 77us) with best_truth FUSED: the block's <=2
// batches' 32 gt boxes+labels live in LDS; each row's 4 workers scan 8 gts
// each (first-occurrence argmax), exact shfl combine (larger v, smaller idx).
// Rides under the latency-bound staging (R14: +VALU = +0 time). Removes
// k_match's best_truth role and the whole bt_* round-trip.
__global__ __launch_bounds__(TPB, 6) void
k_main(const float* __restrict__ loc_data,
       const float* __restrict__ conf_data,
       const float* __restrict__ priors,
       const float* __restrict__ gt_boxes,
       const int* __restrict__ gt_labels,
       const unsigned long long* __restrict__ best_key,
       float* __restrict__ lossc,
       float* __restrict__ ce_neg,
       int* __restrict__ num_pos,
       float* __restrict__ accum) {
    __shared__ float srow[RPB * C_];      // 41472 B
    __shared__ float4 s_gt[2][O_];        // gt boxes (point form), 1KB
    __shared__ int s_gl[2][O_];           // gt labels
    __shared__ int s_fp[2][O_];           // forced prior per (batch-half, o)
    __shared__ int s_fl[2][O_];           // its label
    __shared__ float s_lB, s_ceP;
    __shared__ int s_np0, s_np1;
    const int row0 = blockIdx.x * RPB;
    const int b0 = row0 / P_;
    const int tid = threadIdx.x;
    const int w = tid >> 6;
    if (tid == 0) { s_lB = 0.0f; s_ceP = 0.0f; s_np0 = 0; s_np1 = 0; }

    {   // async stage: 2592 float4 = 5 full rounds + 32-lane tail
        const float4* src = (const float4*)(conf_data + (size_t)row0 * C_);
        float4* dst4 = (float4*)srow;
        #pragma unroll
        for (int k = 0; k < 5; ++k) {
            __builtin_amdgcn_global_load_lds((AS1)(src + k * 512 + tid),
                                             (AS3)(dst4 + k * 512 + (w << 6)),
                                             16, 0, 0);
        }
        if (tid < 32) {
            __builtin_amdgcn_global_load_lds((AS1)(src + 2560 + tid),
                                             (AS3)(dst4 + 2560), 16, 0, 0);
        }
    }
    // stage gt boxes/labels + force-match table for this block's <=2 batches
    if (tid < 2 * O_) {
        int half = tid >> 5, o = tid & 31;
        int bb = b0 + half;
        int fp = -1, fl = 0;
        float4 g = make_float4(0.f, 0.f, 0.f, 0.f);
        int gl = 0;
        if (bb < B_) {
            unsigned long long key = best_key[bb * O_ + o];
            fp = (int)(0xFFFFFFFFu - (unsigned int)(key & 0xFFFFFFFFu));
            fl = gt_labels[bb * O_ + o];
            g  = ((const float4*)gt_boxes)[bb * O_ + o];
            gl = fl;
        }
        s_fp[half][o] = fp;
        s_fl[half][o] = fl;
        s_gt[half][o] = g;
        s_gl[half][o] = gl;
    }
    __syncthreads();

    const int r = tid >> 2;               // row within tile
    const int q = tid & 3;                // sub-row worker
    const int bp = row0 + r;
    const int b = bp / P_;
    const int p = bp - b * P_;
    const int whichb = b - b0;
    const float* row = srow + r * C_;
    const int j0 = 20 * q;

    // ---- fused best_truth: 4 workers x 8 gts, first-occurrence argmax ----
    const float4 pr4 = ((const float4*)priors)[p];
    float bestv = -1.0f; int besti = 0;
    #pragma unroll
    for (int oo = 0; oo < 8; ++oo) {
        int g = 8 * q + oo;
        float v = iou_gt_prior(s_gt[whichb][g], pr4);
        if (v > bestv) { bestv = v; besti = g; }
    }
    #pragma unroll
    for (int d = 1; d < 4; d <<= 1) {
        float ov = __shfl_xor(bestv, d);
        int oi = __shfl_xor(besti, d);
        if (ov > bestv || (ov == bestv && oi < besti)) { bestv = ov; besti = oi; }
    }

    // ---- logsumexp over 81, 4 workers ----
    float ma = row[j0], mb = row[j0 + 1], mc = row[j0 + 2], md = row[j0 + 3];
    #pragma unroll
    for (int i = 4; i < 20; i += 4) {
        ma = fmaxf(ma, row[j0 + i]);     mb = fmaxf(mb, row[j0 + i + 1]);
        mc = fmaxf(mc, row[j0 + i + 2]); md = fmaxf(md, row[j0 + i + 3]);
    }
    float m = fmaxf(fmaxf(ma, mb), fmaxf(mc, md));
    if (q == 3) m = fmaxf(m, row[80]);
    m = fmaxf(m, __shfl_xor(m, 1));
    m = fmaxf(m, __shfl_xor(m, 2));

    float sa = 0.f, sb = 0.f, sc = 0.f, sd = 0.f;
    #pragma unroll
    for (int i = 0; i < 20; i += 4) {
        sa += __expf(row[j0 + i] - m);     sb += __expf(row[j0 + i + 1] - m);
        sc += __expf(row[j0 + i + 2] - m); sd += __expf(row[j0 + i + 3] - m);
    }
    float s = (sa + sb) + (sc + sd);
    if (q == 3) s += __expf(row[80] - m);
    s += __shfl_xor(s, 1);
    s += __shfl_xor(s, 2);
    float logZ = m + __logf(s);

    if (q == 0) {
        // force-match check: scan oo=31..0, first hit = last-wins
        int foo = -1;
        #pragma unroll
        for (int oo = O_ - 1; oo >= 0; --oo) {
            if (foo < 0 && s_fp[whichb][oo] == p) foo = oo;
        }
        int conf_t, ti;
        bool pos;
        if (foo >= 0) {                   // forced: ov=2.0 -> positive
            conf_t = s_fl[whichb][foo] + 1;
            pos = true;
            ti = foo;
        } else {
            conf_t = s_gl[whichb][besti] + 1;
            if (bestv < POS_TH) conf_t = -1;
            if (bestv < NEG_TH) conf_t = 0;
            pos = conf_t > 0;
            ti = besti;
        }

        float lc = (pos || conf_t < 0) ? 0.0f : (logZ - row[0]);
        int cls = pos ? conf_t : 0;
        float ce = logZ - row[cls];

        lossc[bp] = lc;
        ce_neg[bp] = (conf_t == 0) ? ce : 0.0f;

        if (pos) {
            float4 t = s_gt[whichb][ti];
            float mcx = (t.x + t.z) * 0.5f;
            float mcy = (t.y + t.w) * 0.5f;
            float gx = (mcx - pr4.x) / (0.1f * pr4.z);
            float gy = (mcy - pr4.y) / (0.1f * pr4.w);
            float gw = logf((t.z - t.x) / pr4.z) / 0.2f;
            float gh = logf((t.w - t.y) / pr4.w) / 0.2f;
            float4 ld = ((const float4*)loc_data)[bp];
            float sc2 = sl1(ld.x - gx) + sl1(ld.y - gy) + sl1(ld.z - gw) + sl1(ld.w - gh);
            atomicAdd(&s_lB, sc2);
            atomicAdd(&s_ceP, ce);
            if (b == b0) atomicAdd(&s_np0, 1); else atomicAdd(&s_np1, 1);
        }
    }
    __syncthreads();
    if (tid == 0) {
        if (s_lB != 0.0f) atomicAdd(&accum[0], s_lB);
        if (s_ceP != 0.0f) atomicAdd(&accum[1], s_ceP);
        if (s_np0) atomicAdd(&num_pos[b0], s_np0);
        if (s_np1) atomicAdd(&num_pos[b0 + 1], s_np1);   // tile spans <=2 batches
    }
}

// One block per batch, 1024 threads: register-cached radix select (exact
// stable-argsort semantics). Sentinels (i >= P_) use fb=0, cv=0 (R14-verified).
__global__ __launch_bounds__(OT) void
k_ohem(const float* __restrict__ lossc, const float* __restrict__ ce_neg,
       const int* __restrict__ num_pos, const float* __restrict__ accum,
       float* __restrict__ ce_sum, int* __restrict__ done,
       float* __restrict__ out) {
    const int b = blockIdx.x;
    const int tid = threadIdx.x;
    const float* lc = lossc + (size_t)b * P_;
    const float* cn = ce_neg + (size_t)b * P_;
    __shared__ int h[2048];
    __shared__ int wsum[16];
    __shared__ int s_bin, s_kk;
    __shared__ float red[OT];

    int k = 3 * num_pos[b];
    if (k > P_ - 1) k = P_ - 1;

    float result = 0.0f;
    if (k > 0) {
        unsigned int fb[NJ]; float cv[NJ];
        #pragma unroll
        for (int j = 0; j < NJ; ++j) {
            int i = tid + j * OT;
            bool valid = (i < P_);
            fb[j] = valid ? __float_as_uint(lc[i]) : 0u;   // bottom-ranked sentinel
            cv[j] = valid ? cn[i] : 0.0f;
        }
        // round 0: 1024-bin hist of fb>>21 (monotone, lossc >= 0)
        h[tid] = 0; h[tid + 1024] = 0;
        __syncthreads();
        #pragma unroll
        for (int j = 0; j < NJ; ++j) atomicAdd(&h[fb[j] >> 21], 1);
        __syncthreads();
        pick_top<2>(h, k, tid, &s_bin, &s_kk, wsum);
        const unsigned int T = (unsigned int)s_bin;
        int kk = s_kk;

        // pass A: sum ce for bins > T; hist bits 20..10 of bin==T
        h[tid] = 0; h[tid + 1024] = 0;
        __syncthreads();
        float sum = 0.0f;
        #pragma unroll
        for (int j = 0; j < NJ; ++j) {
            unsigned int bin = fb[j] >> 21;
            if (bin > T) sum += cv[j];
            else if (bin == T) atomicAdd(&h[(fb[j] >> 10) & 2047], 1);
        }
        __syncthreads();
        pick_top<2>(h, kk, tid, &s_bin, &s_kk, wsum);
        const unsigned int pre21 = (T << 11) | (unsigned int)s_bin;
        kk = s_kk;

        // pass B: hist bits 9..0 of elements matching top 22 bits
        h[tid] = 0; h[tid + 1024] = 0;
        __syncthreads();
        #pragma unroll
        for (int j = 0; j < NJ; ++j)
            if ((fb[j] >> 10) == pre21) atomicAdd(&h[fb[j] & 1023], 1);
        __syncthreads();
        pick_top<2>(h, kk, tid, &s_bin, &s_kk, wsum);
        const unsigned int V = (pre21 << 10) | (unsigned int)s_bin;
        const int ee = h[s_bin];
        kk = s_kk;

        if (kk == ee) {
            #pragma unroll
            for (int j = 0; j < NJ; ++j)
                if ((fb[j] >> 21) == T && fb[j] >= V) sum += cv[j];
        } else {
            // kk smallest-index elements with fb == V (stable argsort ties);
            // sentinels at fb==0==V lose by index and carry cv=0.
            h[tid] = 0; h[tid + 1024] = 0;
            __syncthreads();
            #pragma unroll
            for (int j = 0; j < NJ; ++j)
                if (fb[j] == V) atomicAdd(&h[(tid + j * OT) >> 6], 1);
            __syncthreads();
            pick_bot<2>(h, kk, tid, &s_bin, &s_kk, wsum);
            const int d6 = s_bin;
            kk = s_kk;
            h[tid] = 0; h[tid + 1024] = 0;
            __syncthreads();
            #pragma unroll
            for (int j = 0; j < NJ; ++j) {
                int i = tid + j * OT;
                if (fb[j] == V && (i >> 6) == d6) atomicAdd(&h[i & 63], 1);
            }
            __syncthreads();
            pick_bot<2>(h, kk, tid, &s_bin, &s_kk, wsum);
            const int Istar = (d6 << 6) | s_bin;
            #pragma unroll
            for (int j = 0; j < NJ; ++j) {
                int i = tid + j * OT;
                if ((fb[j] >> 21) == T && (fb[j] > V || (fb[j] == V && i <= Istar)))
                    sum += cv[j];
            }
        }

        red[tid] = sum;
        __syncthreads();
        for (int s = OT / 2; s > 0; s >>= 1) {
            if (tid < s) red[tid] += red[tid + s];
            __syncthreads();
        }
        result = red[0];
    }

    if (tid == 0) {
        ce_sum[b] = result;
        __threadfence();
        int old = atomicAdd(done, 1);
        if (old == B_ - 1) {                  // last block folds the output
            __threadfence();
            int tp = 0; float ns = 0.0f;
            for (int bb = 0; bb < B_; ++bb) { tp += num_pos[bb]; ns += ce_sum[bb]; }
            float inv = 1.0f / (float)tp;
            out[0] = accum[0] * 1.5f * inv;   // BBOX_ALPHA
            out[1] = (accum[1] + ns) * inv;   // CONF_ALPHA
        }
    }
}

extern "C" void kernel_launch(void* const* d_in, const int* in_sizes, int n_in,
                              void* d_out, int out_size, void* d_ws, size_t ws_size,
                              hipStream_t stream) {
    const float* loc    = (const float*)d_in[0];
    const float* conf   = (const float*)d_in[1];
    const float* priors = (const float*)d_in[2];
    const float* gtb    = (const float*)d_in[3];
    const int*   gtl    = (const int*)d_in[4];
    float* out = (float*)d_out;

    const size_t BP = (size_t)B_ * P_;
    float* W = (float*)d_ws;
    float* lossc   = W;
    float* ce_neg  = W + BP;
    unsigned long long* best_key = (unsigned long long*)(W + 2 * BP);  // 8B-aligned
    int*   num_pos = (int*)(best_key + B_ * O_);
    float* ce_sum  = (float*)(num_pos + B_);
    float* accum   = ce_sum + B_;
    int*   done    = (int*)(accum + 2);

    // zero best_key + num_pos + ce_sum + accum + done in one memset
    size_t zbytes = B_ * O_ * sizeof(unsigned long long) +
                    B_ * sizeof(int) + B_ * sizeof(float) +
                    2 * sizeof(float) + sizeof(int);
    hipMemsetAsync(best_key, 0, zbytes, stream);
    hipLaunchKernelGGL(k_match, dim3(BP_BLK), dim3(256), 0, stream,
                       priors, gtb, best_key);
    hipLaunchKernelGGL(k_main, dim3((int)(BP / RPB)), dim3(TPB), 0, stream,
                       loc, conf, priors, gtb, gtl, best_key,
                       lossc, ce_neg, num_pos, accum);
    hipLaunchKernelGGL(k_ohem, dim3(B_), dim3(OT), 0, stream,
                       lossc, ce_neg, num_pos, accum, ce_sum, done, out);
}